// Round 1
// baseline (326.763 us; speedup 1.0000x reference)
//
#include <hip/hip_runtime.h>

#define IMG_H 512
#define IMG_W 512
#define NCH 3
#define NB 32
#define COLS 256     // output columns per block
#define ROWS 64      // output rows per block
#define ITERS (ROWS + 6)   // 70 row iterations (multiple of 7)

__global__ __launch_bounds__(256) void ssim_kernel(
    const float* __restrict__ x, const float* __restrict__ y,
    float* __restrict__ out)
{
    __shared__ float xb[2][264];
    __shared__ float yb[2][264];
    __shared__ float red[4];

    const int tid = threadIdx.x;
    const int bid = blockIdx.x;
    const int b   = bid / 48;          // 48 = 3 ch * 2 col-tiles * 8 row-tiles
    const int rem = bid % 48;
    const int ch  = rem >> 4;
    const int t   = rem & 15;
    const int tx  = t & 1;
    const int ty  = t >> 1;
    const int c0  = tx * COLS;
    const int r0  = ty * ROWS;
    const size_t ibase = ((size_t)(b * NCH + ch)) * ((size_t)IMG_H * IMG_W);
    const float* __restrict__ xp = x + ibase;
    const float* __restrict__ yp = y + ibase;

    const float C1v = 0.01f * 0.01f;
    const float C2v = 0.03f * 0.03f;

    // 7-deep ring buffers of horizontal sums (statically indexed via unroll-by-7)
    float rx[7], ry[7], rxx[7], ryy[7], rxy[7];
    #pragma unroll
    for (int u = 0; u < 7; ++u) { rx[u]=ry[u]=rxx[u]=ryy[u]=rxy[u]=0.f; }
    float vsx=0.f, vsy=0.f, vsxx=0.f, vsyy=0.f, vsxy=0.f;
    float acc = 0.f;

    const int c = c0 + tid;

    for (int rb = 0; rb < ITERS; rb += 7) {
        #pragma unroll
        for (int u = 0; u < 7; ++u) {
            const int it = rb + u;          // 0..69
            const int rr = r0 - 3 + it;     // input row (may be out of range -> zero pad)
            const int p  = it & 1;

            float xv = 0.f, yv = 0.f;
            const bool rok = (rr >= 0) & (rr < IMG_H);
            const size_t roff = (size_t)rr * IMG_W;
            if (rok) { xv = xp[roff + c]; yv = yp[roff + c]; }
            xb[p][tid + 3] = xv;
            yb[p][tid + 3] = yv;
            if (tid < 3) {
                const int cl = c0 - 3 + tid;
                float xl = 0.f, yl = 0.f;
                if (rok && cl >= 0) { xl = xp[roff + cl]; yl = yp[roff + cl]; }
                xb[p][tid] = xl; yb[p][tid] = yl;
            } else if (tid >= COLS - 3) {
                const int cr = c + 3;
                float xr = 0.f, yr = 0.f;
                if (rok && cr < IMG_W) { xr = xp[roff + cr]; yr = yp[roff + cr]; }
                xb[p][tid + 6] = xr; yb[p][tid + 6] = yr;
            }
            __syncthreads();

            // horizontal 7-tap sums for the 5 pooled quantities
            float hx=0.f, hy=0.f, hxx=0.f, hyy=0.f, hxy=0.f;
            #pragma unroll
            for (int k = 0; k < 7; ++k) {
                const float xk = xb[p][tid + k];
                const float yk = yb[p][tid + k];
                hx += xk; hy += yk;
                hxx = fmaf(xk, xk, hxx);
                hyy = fmaf(yk, yk, hyy);
                hxy = fmaf(xk, yk, hxy);
            }

            // vertical sliding window: after this, window covers rows rr-6..rr
            vsx  += hx  - rx[u];  rx[u]  = hx;
            vsy  += hy  - ry[u];  ry[u]  = hy;
            vsxx += hxx - rxx[u]; rxx[u] = hxx;
            vsyy += hyy - ryy[u]; ryy[u] = hyy;
            vsxy += hxy - rxy[u]; rxy[u] = hxy;

            if (it >= 6) {   // output row r = rr-3 in [r0, r0+ROWS)
                const float inv49 = 1.f / 49.f;
                const float mx = vsx * inv49, my = vsy * inv49;
                const float sxx = vsxx * inv49 - mx * mx;
                const float syy = vsyy * inv49 - my * my;
                const float sxy = vsxy * inv49 - mx * my;
                const float num = (2.f * mx * my + C1v) * (2.f * sxy + C2v);
                const float den = (mx * mx + my * my + C1v) * (sxx + syy + C2v);
                acc += num / (den + 1e-12f);
            }
        }
    }

    // block reduction: wave shuffle then cross-wave via LDS
    #pragma unroll
    for (int off = 32; off > 0; off >>= 1)
        acc += __shfl_down(acc, off, 64);
    const int wid = tid >> 6;
    if ((tid & 63) == 0) red[wid] = acc;
    __syncthreads();
    if (tid == 0) {
        const float v = red[0] + red[1] + red[2] + red[3];
        atomicAdd(&out[b], v * (1.0f / ((float)NCH * IMG_H * IMG_W)));
    }
}

extern "C" void kernel_launch(void* const* d_in, const int* in_sizes, int n_in,
                              void* d_out, int out_size, void* d_ws, size_t ws_size,
                              hipStream_t stream) {
    const float* x = (const float*)d_in[0];
    const float* y = (const float*)d_in[1];
    float* out = (float*)d_out;
    // harness poisons d_out with 0xAA before every timed launch -> zero it
    hipMemsetAsync(out, 0, sizeof(float) * NB, stream);
    const int grid = NB * NCH * (IMG_W / COLS) * (IMG_H / ROWS);  // 1536
    ssim_kernel<<<grid, 256, 0, stream>>>(x, y, out);
}

// Round 2
// 254.580 us; speedup vs baseline: 1.2835x; 1.2835x over previous
//
#include <hip/hip_runtime.h>

#define IMG_H 512
#define IMG_W 512
#define NCH 3
#define NB 32
#define RSTRIP 16
#define NSTRIP (IMG_H / RSTRIP)   // 32 strips per channel-image

// One wave (64 lanes) owns a full 512-wide strip of RSTRIP output rows.
// Each lane owns 8 contiguous columns. Vertical 7-tap window is maintained as
// 5 running column-sums (x, y, xx, yy, xy), slid by adding row r+4 and
// re-loading/subtracting row r-3 (L2/L3-warm). Horizontal 7-tap done per row
// via lane-neighbor shfl halos + sliding sums. No LDS, no barriers.
__global__ __launch_bounds__(256) void ssim_kernel(const float* __restrict__ x,
                                                   const float* __restrict__ y,
                                                   float* __restrict__ out)
{
    const int tid  = threadIdx.x;
    const int lane = tid & 63;
    const int wid  = (blockIdx.x << 2) + (tid >> 6);
    const int b     = wid / (NCH * NSTRIP);
    const int rem   = wid % (NCH * NSTRIP);
    const int ch    = rem / NSTRIP;
    const int strip = rem % NSTRIP;
    const int r0    = strip * RSTRIP;

    const int ibase = (b * NCH + ch) * (IMG_H * IMG_W) + lane * 8;
    const float* __restrict__ xp = x + ibase;
    const float* __restrict__ yp = y + ibase;

    float vsx[8], vsy[8], vsxx[8], vsyy[8], vsxy[8];
    #pragma unroll
    for (int i = 0; i < 8; ++i) { vsx[i]=vsy[i]=vsxx[i]=vsyy[i]=vsxy[i]=0.f; }

    // ---- prologue: accumulate rows r0-3 .. r0+3 (zero-padded outside) ----
    #pragma unroll
    for (int j = -3; j <= 3; ++j) {
        const int rr = r0 + j;
        if (rr >= 0 && rr < IMG_H) {
            float xn[8], yn[8];
            *(float4*)&xn[0] = *(const float4*)(xp + rr * IMG_W);
            *(float4*)&xn[4] = *(const float4*)(xp + rr * IMG_W + 4);
            *(float4*)&yn[0] = *(const float4*)(yp + rr * IMG_W);
            *(float4*)&yn[4] = *(const float4*)(yp + rr * IMG_W + 4);
            #pragma unroll
            for (int i = 0; i < 8; ++i) {
                vsx[i] += xn[i];
                vsy[i] += yn[i];
                vsxx[i] = fmaf(xn[i], xn[i], vsxx[i]);
                vsyy[i] = fmaf(yn[i], yn[i], vsyy[i]);
                vsxy[i] = fmaf(xn[i], yn[i], vsxy[i]);
            }
        }
    }

    const float C1v = 1e-4f;
    const float C2v = 9e-4f;
    const float inv49 = 1.0f / 49.0f;
    float acc = 0.f;

    #pragma unroll 2
    for (int r = r0; r < r0 + RSTRIP; ++r) {
        // ---- issue slide loads early (row r+4 enters, row r-3 leaves) ----
        const bool slide = (r < r0 + RSTRIP - 1);
        const int ra = r + 4, rs = r - 3;
        float xn[8], yn[8], xo[8], yo[8];
        #pragma unroll
        for (int i = 0; i < 8; ++i) { xn[i]=yn[i]=xo[i]=yo[i]=0.f; }
        if (slide && ra < IMG_H) {
            *(float4*)&xn[0] = *(const float4*)(xp + ra * IMG_W);
            *(float4*)&xn[4] = *(const float4*)(xp + ra * IMG_W + 4);
            *(float4*)&yn[0] = *(const float4*)(yp + ra * IMG_W);
            *(float4*)&yn[4] = *(const float4*)(yp + ra * IMG_W + 4);
        }
        if (slide && rs >= 0) {
            *(float4*)&xo[0] = *(const float4*)(xp + rs * IMG_W);
            *(float4*)&xo[4] = *(const float4*)(xp + rs * IMG_W + 4);
            *(float4*)&yo[0] = *(const float4*)(yp + rs * IMG_W);
            *(float4*)&yo[4] = *(const float4*)(yp + rs * IMG_W + 4);
        }

        // ---- halo exchange of vertical sums with neighbor lanes ----
        float hlx[3], hly[3], hlxx[3], hlyy[3], hlxy[3];
        float hrx[3], hry[3], hrxx[3], hryy[3], hrxy[3];
        #pragma unroll
        for (int k = 0; k < 3; ++k) {
            float t;
            t = __shfl_up(vsx[5+k], 1, 64);  hlx[k]  = (lane == 0)  ? 0.f : t;
            t = __shfl_up(vsy[5+k], 1, 64);  hly[k]  = (lane == 0)  ? 0.f : t;
            t = __shfl_up(vsxx[5+k], 1, 64); hlxx[k] = (lane == 0)  ? 0.f : t;
            t = __shfl_up(vsyy[5+k], 1, 64); hlyy[k] = (lane == 0)  ? 0.f : t;
            t = __shfl_up(vsxy[5+k], 1, 64); hlxy[k] = (lane == 0)  ? 0.f : t;
            t = __shfl_down(vsx[k], 1, 64);  hrx[k]  = (lane == 63) ? 0.f : t;
            t = __shfl_down(vsy[k], 1, 64);  hry[k]  = (lane == 63) ? 0.f : t;
            t = __shfl_down(vsxx[k], 1, 64); hrxx[k] = (lane == 63) ? 0.f : t;
            t = __shfl_down(vsyy[k], 1, 64); hryy[k] = (lane == 63) ? 0.f : t;
            t = __shfl_down(vsxy[k], 1, 64); hrxy[k] = (lane == 63) ? 0.f : t;
        }

        // ---- horizontal sliding 7-tap + SSIM per column ----
        float hx  = hlx[0]+hlx[1]+hlx[2]+vsx[0]+vsx[1]+vsx[2]+vsx[3];
        float hy  = hly[0]+hly[1]+hly[2]+vsy[0]+vsy[1]+vsy[2]+vsy[3];
        float hxx = hlxx[0]+hlxx[1]+hlxx[2]+vsxx[0]+vsxx[1]+vsxx[2]+vsxx[3];
        float hyy = hlyy[0]+hlyy[1]+hlyy[2]+vsyy[0]+vsyy[1]+vsyy[2]+vsyy[3];
        float hxy = hlxy[0]+hlxy[1]+hlxy[2]+vsxy[0]+vsxy[1]+vsxy[2]+vsxy[3];
        #pragma unroll
        for (int i = 0; i < 8; ++i) {
            if (i > 0) {
                // ve index: k<3 -> hl[k]; k<11 -> vs[k-3]; else hr[k-11]
                const float ax  = (i+6 < 11) ? vsx[i+3]  : hrx[i-5];
                const float ay  = (i+6 < 11) ? vsy[i+3]  : hry[i-5];
                const float axx = (i+6 < 11) ? vsxx[i+3] : hrxx[i-5];
                const float ayy = (i+6 < 11) ? vsyy[i+3] : hryy[i-5];
                const float axy = (i+6 < 11) ? vsxy[i+3] : hrxy[i-5];
                const float sx_ = (i-1 < 3) ? hlx[i-1]  : vsx[i-4];
                const float sy_ = (i-1 < 3) ? hly[i-1]  : vsy[i-4];
                const float sxx_= (i-1 < 3) ? hlxx[i-1] : vsxx[i-4];
                const float syy_= (i-1 < 3) ? hlyy[i-1] : vsyy[i-4];
                const float sxy_= (i-1 < 3) ? hlxy[i-1] : vsxy[i-4];
                hx += ax - sx_;  hy += ay - sy_;
                hxx += axx - sxx_; hyy += ayy - syy_; hxy += axy - sxy_;
            }
            const float mx = hx * inv49, my = hy * inv49;
            const float sxx = fmaf(-mx, mx, hxx * inv49);
            const float syy = fmaf(-my, my, hyy * inv49);
            const float sxy = fmaf(-mx, my, hxy * inv49);
            const float num = fmaf(2.f * mx, my, C1v) * fmaf(2.f, sxy, C2v);
            const float den = fmaf(mx, mx, fmaf(my, my, C1v)) * (sxx + syy + C2v);
            acc += num * __builtin_amdgcn_rcpf(den + 1e-12f);
        }

        // ---- vertical window update ----
        #pragma unroll
        for (int i = 0; i < 8; ++i) {
            const float dx = xn[i] - xo[i], sx = xn[i] + xo[i];
            const float dy = yn[i] - yo[i], sy = yn[i] + yo[i];
            vsx[i] += dx;
            vsy[i] += dy;
            vsxx[i] = fmaf(dx, sx, vsxx[i]);
            vsyy[i] = fmaf(dy, sy, vsyy[i]);
            vsxy[i] = fmaf(xn[i], yn[i], vsxy[i] - xo[i] * yo[i]);
        }
    }

    // ---- wave reduction + one atomic per wave ----
    #pragma unroll
    for (int off = 32; off; off >>= 1) acc += __shfl_down(acc, off, 64);
    if (lane == 0)
        atomicAdd(&out[b], acc * (1.0f / ((float)NCH * IMG_H * IMG_W)));
}

extern "C" void kernel_launch(void* const* d_in, const int* in_sizes, int n_in,
                              void* d_out, int out_size, void* d_ws, size_t ws_size,
                              hipStream_t stream) {
    const float* x = (const float*)d_in[0];
    const float* y = (const float*)d_in[1];
    float* out = (float*)d_out;
    hipMemsetAsync(out, 0, sizeof(float) * NB, stream);
    const int nwaves = NB * NCH * NSTRIP;       // 3072
    ssim_kernel<<<nwaves / 4, 256, 0, stream>>>(x, y, out);
}